// Round 5
// baseline (27136.340 us; speedup 1.0000x reference)
//
#include <hip/hip_runtime.h>
#include <hip/hip_bf16.h>
#include <hip/hip_cooperative_groups.h>

// TimeGAN generator: 3-layer GRU (H=256) + feedback MLP, B=2048, T=256.
// Round 5: cooperative launch + grid.sync() per step to keep all blocks in
// lockstep -> each weight line is fetched once per XCD per step and hit in
// L2 by the other 15 blocks (R4 showed 4.6x refetch from inter-block drift,
// making the per-CU outstanding-miss window the bottleneck at IC latency).
// Streaming structure unchanged from R4: 3KB sub-slices, 4-deep LDS ring,
// issue s+3 / wait vmcnt(9), per-block K-rotation.

namespace cg = cooperative_groups;

typedef __attribute__((ext_vector_type(8))) short short8;   // 8 x bf16
typedef __attribute__((ext_vector_type(4))) float f32x4;

#define BQ   16
#define NTHR 512
#define TT   256
#define NBLK 128
#define NSUB 84     // sub-slices per step (3 frags = 3KB each, per wave)

// packed-weight fragment bases (in 64-lane-frag units; elements = frag*8)
#define FB_WI0  0        // [768 x  64], KT=2
#define FB_WH0  6144     // [768 x 256], KT=8
#define FB_WI1  30720
#define FB_WH1  55296
#define FB_WI2  79872
#define FB_WH2  104448
#define FB_W1   129024   // [256 x 256]
#define FB_W2   137216   // [ 64 x 256]
#define TOTAL_FRAGS 139264

__device__ __forceinline__ short bf16_rne(float v) {
  union { float f; unsigned u; } c; c.f = v;
  unsigned u = c.u;
  u += 0x7FFFu + ((u >> 16) & 1u);
  return (short)(u >> 16);
}
__device__ __forceinline__ float fast_sigmoid(float x) {
  return 1.0f / (1.0f + __expf(-x));
}
__device__ __forceinline__ float fast_tanh(float x) {
  return 1.0f - 2.0f / (__expf(2.0f * x) + 1.0f);
}

// A-fragment read from a bf16 LDS tile [BQ][S] with XOR swizzle
__device__ __forceinline__ short8 lds_a(const short* buf, int S, int row, int k) {
  int idx = row * S + (k ^ ((row & 7) << 3));
  return *(const short8*)(buf + idx);
}

struct CB { float brz0, brz1, bzz0, bzz1, bin0, bin1, bhn0, bhn1; };

__device__ __forceinline__ CB make_cb(const float* bi, const float* bh, int wave, int l15) {
  CB cb;
  int c0 = wave * 32 + l15, c1 = c0 + 16;
  cb.brz0 = bi[c0] + bh[c0];
  cb.brz1 = bi[c1] + bh[c1];
  cb.bzz0 = bi[256 + c0] + bh[256 + c0];
  cb.bzz1 = bi[256 + c1] + bh[256 + c1];
  cb.bin0 = bi[512 + c0];
  cb.bin1 = bi[512 + c1];
  cb.bhn0 = bh[512 + c0];
  cb.bhn1 = bh[512 + c1];
  return cb;
}

#define B_ADDR(fb, nt, kt, KT) \
  ((const short8*)(wpack + ((size_t)(fb) + (size_t)((nt) * (KT) + (kt)) * 64 + lane) * 8))

// raw barrier: drains LDS ops only; weight-load vmcnt stays outstanding
__device__ __forceinline__ void block_sync_lds() {
  asm volatile("s_waitcnt lgkmcnt(0)" ::: "memory");
  __builtin_amdgcn_sched_barrier(0);
  __builtin_amdgcn_s_barrier();
  __builtin_amdgcn_sched_barrier(0);
}

// Issue one 3KB sub-slice (3 x global_load_lds_dwordx4). Sub-slice map per
// step (84 subs): cell0 gi 0..3 (KT=2), gh 4..19; cell1 gi 20..35, gh 36..51;
// cell2 gi 52..67, gh 68..83. Each kt = 2 subs (h=0: frags 0-2, h=1: 3-5).
// Per-block rotation r2/r8 spreads concurrent blocks across kt-slices.
__device__ __forceinline__ void issue_sub(const short* __restrict__ wpack,
                                          int s, int r2, int r8,
                                          int wave, int lane, short* ringbuf) {
  s = s % NSUB;   // compile-time folded (s is a constant at each call site)
  int fb, KT, rot, u;
  if (s < 4)       { fb = FB_WI0; KT = 2; u = s;      rot = r2; }
  else if (s < 20) { fb = FB_WH0; KT = 8; u = s - 4;  rot = r8; }
  else if (s < 36) { fb = FB_WI1; KT = 8; u = s - 20; rot = r8; }
  else if (s < 52) { fb = FB_WH1; KT = 8; u = s - 36; rot = r8; }
  else if (s < 68) { fb = FB_WI2; KT = 8; u = s - 52; rot = r8; }
  else             { fb = FB_WH2; KT = 8; u = s - 68; rot = r8; }
  int k = u >> 1, h = u & 1;
  int kp = (k + rot) & (KT - 1);
  __builtin_amdgcn_sched_barrier(0);
#pragma unroll
  for (int j = 0; j < 3; ++j) {
    int fg = h * 3 + j;
    int nt = (fg >> 1) * 16 + wave * 2 + (fg & 1);
    const short* g = wpack + ((size_t)fb + (size_t)(nt * KT + kp) * 64 + lane) * 8;
    __builtin_amdgcn_global_load_lds(
        (const __attribute__((address_space(1))) void*)g,
        (__attribute__((address_space(3))) void*)(ringbuf + j * 512), 16, 0, 0);
  }
  __builtin_amdgcn_sched_barrier(0);
}

// One GRU cell. SB = first sub-slice of this cell; KTGI = gi K-tiles (2 or 8).
template<int SB, int KTGI>
__device__ __forceinline__ void cell_stream(
    const short* gi_src, int gi_S, const short* gh_src,
    const short* __restrict__ wpack, short (*ring)[1536],
    float (&hm)[8], short* hb_l, const CB& cb,
    int r2, int r8, int wave, int lane, int l15, int lhi, int r0q)
{
  f32x4 z4 = {0.f, 0.f, 0.f, 0.f};
  f32x4 agi[6], agh[6];
#pragma unroll
  for (int j = 0; j < 6; ++j) { agi[j] = z4; agh[j] = z4; }

  const int rgi = (KTGI == 2) ? r2 : r8;
  // ---- gi GEMM ----
#pragma unroll
  for (int k = 0; k < KTGI; ++k) {
    int kp = (k + rgi) & (KTGI - 1);
    short8 a;
#pragma unroll
    for (int h = 0; h < 2; ++h) {
      const int s = SB + k * 2 + h;
      issue_sub(wpack, s + 3, r2, r8, wave, lane, ring[(s + 3) & 3]);
      asm volatile("s_waitcnt vmcnt(9)" ::: "memory");
      __builtin_amdgcn_sched_barrier(0);
      if (h == 0) a = lds_a(gi_src, gi_S, l15, kp * 32 + lhi * 8);
      const short* bp = ring[s & 3] + lane * 8;
#pragma unroll
      for (int j = 0; j < 3; ++j)
        agi[h * 3 + j] = __builtin_amdgcn_mfma_f32_16x16x32_bf16(
            a, *(const short8*)(bp + j * 512), agi[h * 3 + j], 0, 0, 0);
    }
  }
  // ---- gh GEMM ----
#pragma unroll
  for (int k = 0; k < 8; ++k) {
    int kp = (k + r8) & 7;
    short8 a;
#pragma unroll
    for (int h = 0; h < 2; ++h) {
      const int s = SB + KTGI * 2 + k * 2 + h;
      issue_sub(wpack, s + 3, r2, r8, wave, lane, ring[(s + 3) & 3]);
      asm volatile("s_waitcnt vmcnt(9)" ::: "memory");
      __builtin_amdgcn_sched_barrier(0);
      if (h == 0) a = lds_a(gh_src, 256, l15, kp * 32 + lhi * 8);
      const short* bp = ring[s & 3] + lane * 8;
#pragma unroll
      for (int j = 0; j < 3; ++j)
        agh[h * 3 + j] = __builtin_amdgcn_mfma_f32_16x16x32_bf16(
            a, *(const short8*)(bp + j * 512), agh[h * 3 + j], 0, 0, 0);
    }
  }

  block_sync_lds();  // all waves done reading old h before overwrite

#pragma unroll
  for (int tl = 0; tl < 2; ++tl) {
    int c = wave * 32 + tl * 16 + l15;
    float brz = tl ? cb.brz1 : cb.brz0;
    float bzz = tl ? cb.bzz1 : cb.bzz0;
    float bin = tl ? cb.bin1 : cb.bin0;
    float bhn = tl ? cb.bhn1 : cb.bhn0;
#pragma unroll
    for (int j = 0; j < 4; ++j) {
      int row = r0q + j;
      float r = fast_sigmoid(agi[tl][j] + agh[tl][j] + brz);
      float z = fast_sigmoid(agi[2 + tl][j] + agh[2 + tl][j] + bzz);
      float n = fast_tanh(agi[4 + tl][j] + bin + r * (agh[4 + tl][j] + bhn));
      float hold = hm[tl * 4 + j];
      float hnew = n + z * (hold - n);
      hm[tl * 4 + j] = hnew;
      hb_l[row * 256 + (c ^ ((row & 7) << 3))] = bf16_rne(hnew);
    }
  }
  block_sync_lds();  // h(new) visible to next stage
}

__global__ void pack_weights(const float* __restrict__ Wi0, const float* __restrict__ Wh0,
                             const float* __restrict__ Wih12, const float* __restrict__ Whh12,
                             const float* __restrict__ W1, const float* __restrict__ W2,
                             short* __restrict__ outp)
{
  int f = blockIdx.x * blockDim.x + threadIdx.x;
  if (f >= TOTAL_FRAGS) return;
  const float* src; int K; int rel;
  if (f < FB_WH0)        { src = Wi0;            K = 64;  rel = f; }
  else if (f < FB_WI1)   { src = Wh0;            K = 256; rel = f - FB_WH0; }
  else if (f < FB_WH1)   { src = Wih12;          K = 256; rel = f - FB_WI1; }
  else if (f < FB_WI2)   { src = Whh12;          K = 256; rel = f - FB_WH1; }
  else if (f < FB_WH2)   { src = Wih12 + 196608; K = 256; rel = f - FB_WI2; }
  else if (f < FB_W1)    { src = Whh12 + 196608; K = 256; rel = f - FB_WH2; }
  else if (f < FB_W2)    { src = W1;             K = 256; rel = f - FB_W1; }
  else                   { src = W2;             K = 256; rel = f - FB_W2; }
  int lane = rel & 63;
  int q = rel >> 6;
  int KT = K >> 5;
  int kt = q % KT;
  int nt = q / KT;
  int n  = nt * 16 + (lane & 15);
  int k0 = kt * 32 + (lane >> 4) * 8;
  short8 v;
#pragma unroll
  for (int e = 0; e < 8; ++e) v[e] = bf16_rne(src[(size_t)n * K + k0 + e]);
  *(short8*)(outp + (size_t)f * 8) = v;
}

__global__ __launch_bounds__(NTHR, 1)
void timegan_main(const float* __restrict__ noise,
                  const short* __restrict__ wpack,
                  const float* __restrict__ b_ih0, const float* __restrict__ b_hh0,
                  const float* __restrict__ b_ih12, const float* __restrict__ b_hh12,
                  const float* __restrict__ b1v, const float* __restrict__ b2v,
                  float* __restrict__ out)
{
  __shared__ __align__(16) short wring[8][4][1536];   // 96 KB, 4-deep/wave
  __shared__ __align__(16) short xbuf[BQ * 64];
  __shared__ __align__(16) short hbuf0[BQ * 256];
  __shared__ __align__(16) short hbuf1[BQ * 256];
  __shared__ __align__(16) short hbuf2[BQ * 256];
  __shared__ __align__(16) short abuf[BQ * 256];
  __shared__ __align__(16) float ybuf[BQ * 64];

  cg::grid_group grid = cg::this_grid();

  const int tid = threadIdx.x;
  const int lane = tid & 63, wave = tid >> 6;
  const int l15 = lane & 15, lhi = lane >> 4, r0q = lhi * 4;
  const int brow = blockIdx.x * BQ;
  const int r8 = blockIdx.x & 7;     // per-block kt rotation (KT=8 GEMMs)
  const int r2 = blockIdx.x & 1;     // per-block kt rotation (KT=2 GEMM)

  float hm0[8], hm1[8], hm2[8];
#pragma unroll
  for (int j = 0; j < 8; ++j) { hm0[j] = 0.f; hm1[j] = 0.f; hm2[j] = 0.f; }

  for (int i = tid; i < BQ * 256; i += NTHR) {
    hbuf0[i] = 0; hbuf1[i] = 0; hbuf2[i] = 0;
  }
  for (int i = tid; i < BQ * 64; i += NTHR) {
    int r = i >> 6, c = i & 63;
    xbuf[r * 64 + (c ^ ((r & 7) << 3))] = bf16_rne(noise[(size_t)(brow + r) * 64 + c]);
  }

  CB cb0 = make_cb(b_ih0, b_hh0, wave, l15);
  CB cb1 = make_cb(b_ih12, b_hh12, wave, l15);
  CB cb2 = make_cb(b_ih12 + 768, b_hh12 + 768, wave, l15);
  float bm1_0 = b1v[wave * 32 + l15];
  float bm1_1 = b1v[wave * 32 + 16 + l15];
  float bm2 = (wave < 4) ? b2v[wave * 16 + l15] : 0.f;

  // persistent register weights: MLP1 (16 frags) + MLP2 (8 frags, waves 0-3)
  short8 m1[16];
#pragma unroll
  for (int kt = 0; kt < 8; ++kt) {
    m1[kt * 2]     = *B_ADDR(FB_W1, wave * 2,     kt, 8);
    m1[kt * 2 + 1] = *B_ADDR(FB_W1, wave * 2 + 1, kt, 8);
  }
  short8 m2[8];
  if (wave < 4) {
#pragma unroll
    for (int kt = 0; kt < 8; ++kt) m2[kt] = *B_ADDR(FB_W2, wave, kt, 8);
  }

  // drain init-time vmem so the counted-vmcnt stream starts clean
  asm volatile("s_waitcnt vmcnt(0)" ::: "memory");
  __builtin_amdgcn_sched_barrier(0);
  block_sync_lds();

  // prologue: 3 sub-slices in flight
  issue_sub(wpack, 0, r2, r8, wave, lane, wring[wave][0]);
  issue_sub(wpack, 1, r2, r8, wave, lane, wring[wave][1]);
  issue_sub(wpack, 2, r2, r8, wave, lane, wring[wave][2]);

#pragma unroll 1
  for (int t = 0; t < TT; ++t) {
    cell_stream<0, 2>(xbuf, 64,   hbuf0, wpack, wring[wave], hm0, hbuf0, cb0,
                      r2, r8, wave, lane, l15, lhi, r0q);
    cell_stream<20, 8>(hbuf0, 256, hbuf1, wpack, wring[wave], hm1, hbuf1, cb1,
                       r2, r8, wave, lane, l15, lhi, r0q);
    cell_stream<52, 8>(hbuf1, 256, hbuf2, wpack, wring[wave], hm2, hbuf2, cb2,
                       r2, r8, wave, lane, l15, lhi, r0q);

    // ---- MLP1: a1 = relu(h2 @ W1^T + b1), weights in registers ----
    f32x4 z4 = {0.f, 0.f, 0.f, 0.f};
    f32x4 am[2]; am[0] = z4; am[1] = z4;
#pragma unroll
    for (int kt = 0; kt < 8; ++kt) {
      short8 a = lds_a(hbuf2, 256, l15, kt * 32 + lhi * 8);
      am[0] = __builtin_amdgcn_mfma_f32_16x16x32_bf16(a, m1[kt * 2],     am[0], 0, 0, 0);
      am[1] = __builtin_amdgcn_mfma_f32_16x16x32_bf16(a, m1[kt * 2 + 1], am[1], 0, 0, 0);
    }
#pragma unroll
    for (int tl = 0; tl < 2; ++tl) {
      int c = wave * 32 + tl * 16 + l15;
      float bb = tl ? bm1_1 : bm1_0;
#pragma unroll
      for (int j = 0; j < 4; ++j) {
        int row = r0q + j;
        float v = fmaxf(am[tl][j] + bb, 0.f);
        abuf[row * 256 + (c ^ ((row & 7) << 3))] = bf16_rne(v);
      }
    }
    block_sync_lds();

    // ---- MLP2: y = tanh(a1 @ W2^T + b2), weights in registers ----
    if (wave < 4) {
      f32x4 ay = z4;
#pragma unroll
      for (int kt = 0; kt < 8; ++kt) {
        short8 a = lds_a(abuf, 256, l15, kt * 32 + lhi * 8);
        ay = __builtin_amdgcn_mfma_f32_16x16x32_bf16(a, m2[kt], ay, 0, 0, 0);
      }
      int c = wave * 16 + l15;
#pragma unroll
      for (int j = 0; j < 4; ++j) {
        int row = r0q + j;
        float y = fast_tanh(ay[j] + bm2);
        ybuf[row * 64 + c] = y;
        xbuf[row * 64 + (c ^ ((row & 7) << 3))] = bf16_rne(y);  // feedback
      }
    }
    block_sync_lds();

    // ---- store y(t): wave w stores rows 2w, 2w+1 as full 256B rows ----
    {
      int r0 = wave * 2;
      size_t base = ((size_t)(brow + r0) * TT + t) * 64;
      out[base + lane] = ybuf[r0 * 64 + lane];
      out[base + (size_t)TT * 64 + lane] = ybuf[(r0 + 1) * 64 + lane];
    }

    // ---- keep all blocks in lockstep: one grid sync per step ----
    grid.sync();
  }

  // drain any remaining prefetch before wave exit
  asm volatile("s_waitcnt vmcnt(0)" ::: "memory");
}

extern "C" void kernel_launch(void* const* d_in, const int* in_sizes, int n_in,
                              void* d_out, int out_size, void* d_ws, size_t ws_size,
                              hipStream_t stream)
{
  const float* noise  = (const float*)d_in[0];
  const float* W_ih0  = (const float*)d_in[1];
  const float* W_hh0  = (const float*)d_in[2];
  const float* b_ih0  = (const float*)d_in[3];
  const float* b_hh0  = (const float*)d_in[4];
  const float* W_ih12 = (const float*)d_in[5];
  const float* W_hh12 = (const float*)d_in[6];
  const float* b_ih12 = (const float*)d_in[7];
  const float* b_hh12 = (const float*)d_in[8];
  const float* W1     = (const float*)d_in[9];
  const float* b1     = (const float*)d_in[10];
  const float* W2     = (const float*)d_in[11];
  const float* b2     = (const float*)d_in[12];
  float* out   = (float*)d_out;
  short* wpack = (short*)d_ws;   // 2,228,224 bytes of bf16 packed weights
  const short* wpack_c = wpack;

  pack_weights<<<(TOTAL_FRAGS + 255) / 256, 256, 0, stream>>>(
      W_ih0, W_hh0, W_ih12, W_hh12, W1, W2, wpack);

  void* args[] = {
    (void*)&noise, (void*)&wpack_c,
    (void*)&b_ih0, (void*)&b_hh0, (void*)&b_ih12, (void*)&b_hh12,
    (void*)&b1,    (void*)&b2,    (void*)&out
  };
  hipLaunchCooperativeKernel((const void*)timegan_main, dim3(NBLK), dim3(NTHR),
                             args, 0, stream);
}

// Round 7
// 13387.938 us; speedup vs baseline: 2.0269x; 2.0269x over previous
//
#include <hip/hip_runtime.h>
#include <hip/hip_bf16.h>

// TimeGAN generator: 3-layer GRU (H=256) + feedback MLP, B=2048, T=256.
// Round 7: weight-STATIONARY sharded design. R2-R6 analysis: any design where
// every CU streams all 2.06MB of weights per step is pinned at ~9 B/cyc/CU
// (L2-miss MLP) -> ~24 ms floor. Here: 16 groups x 16 blocks; block (g,m)
// permanently holds weight columns m*16..m*16+15 of every layer in LDS/regs
// (zero weight streaming); group g owns batch rows g*128..+128. Per step,
// 5 phases; each ends with a group flag-sync (agent-scope release/acquire)
// and an all-gather of the 16-col activation slices through L2.
// h-state A-fragments persist in VGPRs across all 256 steps.

typedef __attribute__((ext_vector_type(8))) short short8;   // 8 x bf16
typedef __attribute__((ext_vector_type(4))) float f32x4;

#define TT   256
#define NTHR 512
#define NBLK 256

// packed-weight fragment bases (in 64-lane-frag units; elements = frag*8)
#define FB_WI0  0        // [768 x  64], KT=2
#define FB_WH0  6144     // [768 x 256], KT=8
#define FB_WI1  30720
#define FB_WH1  55296
#define FB_WI2  79872
#define FB_WH2  104448
#define FB_W1   129024   // [256 x 256]
#define FB_W2   137216   // [ 64 x 256]
#define TOTAL_FRAGS 139264

// d_ws layout (bytes)
#define OFF_FLAGS 2228224u               // 4 KB of u32 flags
#define OFF_H0    (OFF_FLAGS + 4096u)    // [2048][256] bf16 = 1 MB
#define OFF_H1    (OFF_H0 + 1048576u)
#define OFF_H2    (OFF_H1 + 1048576u)
#define OFF_A1    (OFF_H2 + 1048576u)    // [2048][256] bf16
#define OFF_Y     (OFF_A1 + 1048576u)    // [2048][64] bf16

// LDS weight-frag segment bases (in 1KB-frag units)
#define WH0_F 0
#define WI1_F 24
#define WH1_F 48
#define WI2_F 72
#define WH2_F 96        // 120 frags total = 122,880 B

__device__ __forceinline__ short bf16_rne(float v) {
  union { float f; unsigned u; } c; c.f = v;
  unsigned u = c.u;
  u += 0x7FFFu + ((u >> 16) & 1u);
  return (short)(u >> 16);
}
__device__ __forceinline__ float fast_sigmoid(float x) {
  return 1.0f / (1.0f + __expf(-x));
}
__device__ __forceinline__ float fast_tanh(float x) {
  return 1.0f - 2.0f / (__expf(2.0f * x) + 1.0f);
}

__device__ __forceinline__ void gll(const short* src, short* ldst) {
  __builtin_amdgcn_global_load_lds(
      (const __attribute__((address_space(1))) void*)src,
      (__attribute__((address_space(3))) void*)ldst, 16, 0, 0);
}
__device__ __forceinline__ void vm0() {
  asm volatile("s_waitcnt vmcnt(0)" ::: "memory");
  __builtin_amdgcn_sched_barrier(0);
}
__device__ __forceinline__ void lg0() {
  asm volatile("s_waitcnt lgkmcnt(0)" ::: "memory");
  __builtin_amdgcn_sched_barrier(0);
}

// group flag sync: all 16 blocks of the group arrive; agent-scope
// release/acquire makes prior global writes visible to subsequent gathers.
__device__ __forceinline__ void group_sync(unsigned* flag, unsigned target) {
  vm0();                 // drain this wave's global stores
  __syncthreads();       // whole block drained
  if (threadIdx.x == 0) {
    __builtin_amdgcn_fence(__ATOMIC_RELEASE, "agent");
    __hip_atomic_fetch_add(flag, 1u, __ATOMIC_RELAXED, __HIP_MEMORY_SCOPE_AGENT);
    while (__hip_atomic_load(flag, __ATOMIC_RELAXED, __HIP_MEMORY_SCOPE_AGENT) < target)
      __builtin_amdgcn_s_sleep(2);
    __builtin_amdgcn_fence(__ATOMIC_ACQUIRE, "agent");
  }
  __syncthreads();
}

// issue one 32-col chunk of this wave's 16 rows into staging slot.
// staging slot layout: [8 waves][16 rows][4 x 16B], seg XOR-swizzled.
__device__ __forceinline__ void issue_chunk(const short* srcrow0, int stride_sh,
                                            int colc, int slot, short* stg,
                                            int w, int lane) {
  int row = lane >> 2;
  int sseg = (lane & 3) ^ (row & 3);
  const short* g = srcrow0 + row * stride_sh + colc * 32 + sseg * 8;
  gll(g, stg + slot * 4096 + w * 512);
}

#define RD_FRAG(slot) \
  (*(const short8*)(stg + (slot) * 4096 + w * 512 + l15 * 32 + ((lhi ^ (l15 & 3))) * 8))

// all-gather one 256-col layer (this wave's 16 rows) into 8 A-frags
__device__ __forceinline__ void gather8(const short* layer_base, int grow0,
                                        short* stg, int w, int lane, int l15,
                                        int lhi, short8 (&f)[8]) {
  const short* s0 = layer_base + (size_t)grow0 * 256;
  lg0();   // WAR: prior reads of staging slots done before DMA overwrites
#pragma unroll
  for (int c = 0; c < 4; ++c) issue_chunk(s0, 256, c, c, stg, w, lane);
  vm0();
#pragma unroll
  for (int c = 0; c < 4; ++c) f[c] = RD_FRAG(c);
  lg0();
#pragma unroll
  for (int c = 0; c < 4; ++c) issue_chunk(s0, 256, 4 + c, c, stg, w, lane);
  vm0();
#pragma unroll
  for (int c = 0; c < 4; ++c) f[4 + c] = RD_FRAG(c);
}

struct CB4 { float brz, bzz, bin, bhn; };

__device__ __forceinline__ CB4 make_cb4(const float* bi, const float* bh, int col) {
  CB4 cb;
  cb.brz = bi[col] + bh[col];
  cb.bzz = bi[256 + col] + bh[256 + col];
  cb.bin = bi[512 + col];
  cb.bhn = bh[512 + col];
  return cb;
}

__global__ void pack_weights(const float* __restrict__ Wi0, const float* __restrict__ Wh0,
                             const float* __restrict__ Wih12, const float* __restrict__ Whh12,
                             const float* __restrict__ W1, const float* __restrict__ W2,
                             short* __restrict__ outp)
{
  int f = blockIdx.x * blockDim.x + threadIdx.x;
  if (f >= TOTAL_FRAGS) return;
  const float* src; int K; int rel;
  if (f < FB_WH0)        { src = Wi0;            K = 64;  rel = f; }
  else if (f < FB_WI1)   { src = Wh0;            K = 256; rel = f - FB_WH0; }
  else if (f < FB_WH1)   { src = Wih12;          K = 256; rel = f - FB_WI1; }
  else if (f < FB_WI2)   { src = Whh12;          K = 256; rel = f - FB_WH1; }
  else if (f < FB_WH2)   { src = Wih12 + 196608; K = 256; rel = f - FB_WI2; }
  else if (f < FB_W1)    { src = Whh12 + 196608; K = 256; rel = f - FB_WH2; }
  else if (f < FB_W2)    { src = W1;             K = 256; rel = f - FB_W1; }
  else                   { src = W2;             K = 256; rel = f - FB_W2; }
  int lane = rel & 63;
  int q = rel >> 6;
  int KT = K >> 5;
  int kt = q % KT;
  int nt = q / KT;
  int n  = nt * 16 + (lane & 15);
  int k0 = kt * 32 + (lane >> 4) * 8;
  short8 v;
#pragma unroll
  for (int e = 0; e < 8; ++e) v[e] = bf16_rne(src[(size_t)n * K + k0 + e]);
  *(short8*)(outp + (size_t)f * 8) = v;
}

__global__ void zero_flags(unsigned* f) {
  if (threadIdx.x < 1024) f[threadIdx.x] = 0u;
}

#define MFMA(a, b, acc) __builtin_amdgcn_mfma_f32_16x16x32_bf16((a), (b), (acc), 0, 0, 0)

__global__ __launch_bounds__(NTHR, 2)
void timegan_shard(const float* __restrict__ noise, char* __restrict__ ws,
                   const float* __restrict__ b_ih0, const float* __restrict__ b_hh0,
                   const float* __restrict__ b_ih12, const float* __restrict__ b_hh12,
                   const float* __restrict__ b1v, const float* __restrict__ b2v,
                   float* __restrict__ out)
{
  __shared__ __align__(16) short wlds[120 * 512];    // 122,880 B weight frags
  __shared__ __align__(16) short stg[4 * 8 * 512];   // 32,768 B gather staging

  const short* wpack = (const short*)ws;
  unsigned* flags = (unsigned*)(ws + OFF_FLAGS);
  short* h0g = (short*)(ws + OFF_H0);
  short* h1g = (short*)(ws + OFF_H1);
  short* h2g = (short*)(ws + OFF_H2);
  short* a1g = (short*)(ws + OFF_A1);
  short* yg  = (short*)(ws + OFF_Y);

  const int tid = threadIdx.x;
  const int lane = tid & 63, w = tid >> 6;
  const int l15 = lane & 15, lhi = lane >> 4;
  const int gg = blockIdx.x & 15;        // group (batch slice)
  const int m  = blockIdx.x >> 4;        // member (column shard)
  const int grow0 = gg * 128 + w * 16;   // this wave's first global row
  const int col = m * 16 + l15;          // this lane's output column
  unsigned* gflag = flags + gg * 8;

  // ---- one-time: copy this member's weight shard into LDS (wave 0) ----
  if (w == 0) {
    int dst = 0;
#define COPYSEG(FB, KT)                                                      \
    _Pragma("unroll") for (int g_ = 0; g_ < 3; ++g_)                         \
      _Pragma("unroll") for (int kt_ = 0; kt_ < (KT); ++kt_) {               \
        gll(wpack + ((size_t)(FB) + (size_t)((g_ * 16 + m) * (KT) + kt_) * 64 + lane) * 8, \
            wlds + dst * 512);                                               \
        ++dst;                                                               \
      }
    COPYSEG(FB_WH0, 8)
    COPYSEG(FB_WI1, 8)
    COPYSEG(FB_WH1, 8)
    COPYSEG(FB_WI2, 8)
    COPYSEG(FB_WH2, 8)
#undef COPYSEG
  }

  // ---- register weights: Wi0 (all), W1 (all), W2 (m<4) ----
  short8 xw[3][2];
#pragma unroll
  for (int g = 0; g < 3; ++g)
#pragma unroll
    for (int kt = 0; kt < 2; ++kt)
      xw[g][kt] = *(const short8*)(wpack + ((size_t)FB_WI0 + ((g * 16 + m) * 2 + kt) * 64 + lane) * 8);
  short8 w1f[8];
#pragma unroll
  for (int kt = 0; kt < 8; ++kt)
    w1f[kt] = *(const short8*)(wpack + ((size_t)FB_W1 + (m * 8 + kt) * 64 + lane) * 8);
  short8 m2f[8];
  if (m < 4) {
#pragma unroll
    for (int kt = 0; kt < 8; ++kt)
      m2f[kt] = *(const short8*)(wpack + ((size_t)FB_W2 + (m * 8 + kt) * 64 + lane) * 8);
  }

  // ---- x frags from noise (fp32 -> bf16 frag layout) ----
  short8 xf[2];
  {
    const float* np = noise + (size_t)(grow0 + l15) * 64;
#pragma unroll
    for (int kt = 0; kt < 2; ++kt) {
      f32x4 u0 = *(const f32x4*)(np + kt * 32 + lhi * 8);
      f32x4 u1 = *(const f32x4*)(np + kt * 32 + lhi * 8 + 4);
      short8 v;
#pragma unroll
      for (int e = 0; e < 4; ++e) { v[e] = bf16_rne(u0[e]); v[4 + e] = bf16_rne(u1[e]); }
      xf[kt] = v;
    }
  }

  // ---- biases ----
  CB4 cb0 = make_cb4(b_ih0, b_hh0, col);
  CB4 cb1 = make_cb4(b_ih12, b_hh12, col);
  CB4 cb2 = make_cb4(b_ih12 + 768, b_hh12 + 768, col);
  float bm1 = b1v[col];
  float bm2 = (m < 4) ? b2v[col] : 0.f;

  // ---- persistent state ----
  short8 h0f[8], h1f[8], h2f[8];
  float hm0[4], hm1[4], hm2[4];
  {
    short8 z8 = {0, 0, 0, 0, 0, 0, 0, 0};
#pragma unroll
    for (int kt = 0; kt < 8; ++kt) { h0f[kt] = z8; h1f[kt] = z8; h2f[kt] = z8; }
#pragma unroll
    for (int j = 0; j < 4; ++j) { hm0[j] = 0.f; hm1[j] = 0.f; hm2[j] = 0.f; }
  }

  vm0();              // wave0's LDS-DMA + everyone's reg loads complete
  __syncthreads();

  const f32x4 z4 = {0.f, 0.f, 0.f, 0.f};

#define GATE_UPDATE(agi, agh, cb, hm, hg)                                    \
  _Pragma("unroll") for (int j = 0; j < 4; ++j) {                            \
    float r_ = fast_sigmoid(agi[0][j] + agh[0][j] + cb.brz);                 \
    float z_ = fast_sigmoid(agi[1][j] + agh[1][j] + cb.bzz);                 \
    float n_ = fast_tanh(agi[2][j] + cb.bin + r_ * (agh[2][j] + cb.bhn));    \
    float h_ = n_ + z_ * (hm[j] - n_);                                       \
    hm[j] = h_;                                                              \
    hg[(size_t)(grow0 + lhi * 4 + j) * 256 + col] = bf16_rne(h_);            \
  }

#pragma unroll 1
  for (int t = 0; t < TT; ++t) {
    const unsigned tgt = 16u * (unsigned)(t + 1);

    // ================= cell 0 =================
    {
      f32x4 agi[3] = {z4, z4, z4}, agh[3] = {z4, z4, z4};
#pragma unroll
      for (int g = 0; g < 3; ++g) {
        agi[g] = MFMA(xf[0], xw[g][0], agi[g]);
        agi[g] = MFMA(xf[1], xw[g][1], agi[g]);
      }
#pragma unroll
      for (int kt = 0; kt < 8; ++kt) {
#pragma unroll
        for (int g = 0; g < 3; ++g) {
          short8 b = *(const short8*)(wlds + (WH0_F + g * 8 + kt) * 512 + lane * 8);
          agh[g] = MFMA(h0f[kt], b, agh[g]);
        }
      }
      GATE_UPDATE(agi, agh, cb0, hm0, h0g)
    }
    group_sync(gflag + 0, tgt);
    gather8(h0g, grow0, stg, w, lane, l15, lhi, h0f);   // h0 new

    // ================= cell 1 =================
    {
      f32x4 agi[3] = {z4, z4, z4}, agh[3] = {z4, z4, z4};
#pragma unroll
      for (int kt = 0; kt < 8; ++kt) {
#pragma unroll
        for (int g = 0; g < 3; ++g) {
          short8 bi_ = *(const short8*)(wlds + (WI1_F + g * 8 + kt) * 512 + lane * 8);
          short8 bh_ = *(const short8*)(wlds + (WH1_F + g * 8 + kt) * 512 + lane * 8);
          agi[g] = MFMA(h0f[kt], bi_, agi[g]);
          agh[g] = MFMA(h1f[kt], bh_, agh[g]);
        }
      }
      GATE_UPDATE(agi, agh, cb1, hm1, h1g)
    }
    group_sync(gflag + 1, tgt);
    gather8(h1g, grow0, stg, w, lane, l15, lhi, h1f);   // h1 new

    // ================= cell 2 =================
    {
      f32x4 agi[3] = {z4, z4, z4}, agh[3] = {z4, z4, z4};
#pragma unroll
      for (int kt = 0; kt < 8; ++kt) {
#pragma unroll
        for (int g = 0; g < 3; ++g) {
          short8 bi_ = *(const short8*)(wlds + (WI2_F + g * 8 + kt) * 512 + lane * 8);
          short8 bh_ = *(const short8*)(wlds + (WH2_F + g * 8 + kt) * 512 + lane * 8);
          agi[g] = MFMA(h1f[kt], bi_, agi[g]);
          agh[g] = MFMA(h2f[kt], bh_, agh[g]);
        }
      }
      GATE_UPDATE(agi, agh, cb2, hm2, h2g)
    }
    group_sync(gflag + 2, tgt);
    gather8(h2g, grow0, stg, w, lane, l15, lhi, h2f);   // h2 new

    // ================= MLP1 =================
    {
      f32x4 am = z4;
#pragma unroll
      for (int kt = 0; kt < 8; ++kt) am = MFMA(h2f[kt], w1f[kt], am);
#pragma unroll
      for (int j = 0; j < 4; ++j) {
        float v = fmaxf(am[j] + bm1, 0.f);
        a1g[(size_t)(grow0 + lhi * 4 + j) * 256 + col] = bf16_rne(v);
      }
    }
    group_sync(gflag + 3, tgt);

    // ================= MLP2 (members 0-3) =================
    if (m < 4) {
      short8 af[8];
      gather8(a1g, grow0, stg, w, lane, l15, lhi, af);
      f32x4 ay = z4;
#pragma unroll
      for (int kt = 0; kt < 8; ++kt) ay = MFMA(af[kt], m2f[kt], ay);
#pragma unroll
      for (int j = 0; j < 4; ++j) {
        int grow = grow0 + lhi * 4 + j;
        float y = fast_tanh(ay[j] + bm2);
        out[((size_t)grow * TT + t) * 64 + col] = y;
        yg[(size_t)grow * 64 + col] = bf16_rne(y);
      }
    }
    group_sync(gflag + 4, tgt);

    // ---- gather x(t+1) from y ----
    if (t < TT - 1) {
      const short* s0 = yg + (size_t)grow0 * 64;
      lg0();
      issue_chunk(s0, 64, 0, 0, stg, w, lane);
      issue_chunk(s0, 64, 1, 1, stg, w, lane);
      vm0();
      xf[0] = RD_FRAG(0);
      xf[1] = RD_FRAG(1);
    }
  }
}

extern "C" void kernel_launch(void* const* d_in, const int* in_sizes, int n_in,
                              void* d_out, int out_size, void* d_ws, size_t ws_size,
                              hipStream_t stream)
{
  const float* noise  = (const float*)d_in[0];
  const float* W_ih0  = (const float*)d_in[1];
  const float* W_hh0  = (const float*)d_in[2];
  const float* b_ih0  = (const float*)d_in[3];
  const float* b_hh0  = (const float*)d_in[4];
  const float* W_ih12 = (const float*)d_in[5];
  const float* W_hh12 = (const float*)d_in[6];
  const float* b_ih12 = (const float*)d_in[7];
  const float* b_hh12 = (const float*)d_in[8];
  const float* W1     = (const float*)d_in[9];
  const float* b1     = (const float*)d_in[10];
  const float* W2     = (const float*)d_in[11];
  const float* b2     = (const float*)d_in[12];
  float* out = (float*)d_out;
  char* ws = (char*)d_ws;
  short* wpack = (short*)d_ws;

  zero_flags<<<1, 1024, 0, stream>>>((unsigned*)(ws + OFF_FLAGS));
  pack_weights<<<(TOTAL_FRAGS + 255) / 256, 256, 0, stream>>>(
      W_ih0, W_hh0, W_ih12, W_hh12, W1, W2, wpack);

  void* args[] = {
    (void*)&noise, (void*)&ws,
    (void*)&b_ih0, (void*)&b_hh0, (void*)&b_ih12, (void*)&b_hh12,
    (void*)&b1,    (void*)&b2,    (void*)&out
  };
  hipLaunchCooperativeKernel((const void*)timegan_shard, dim3(NBLK), dim3(NTHR),
                             args, 0, stream);
}

// Round 8
// 5469.674 us; speedup vs baseline: 4.9612x; 2.4477x over previous
//
#include <hip/hip_runtime.h>
#include <hip/hip_bf16.h>

// TimeGAN generator: 3-layer GRU (H=256) + feedback MLP, B=2048, T=256.
// Round 8: weight-stationary sharded (R7) minus the coordination cost.
// - No fences: activation stores sc0+sc1 (write-through to coherent point),
//   gathers direct-to-VGPR with sc0+sc1 (bypass non-coherent L1/L2), flag
//   sync = vmcnt-drain -> global_atomic_add sc1 -> spin sc0sc1 load.
// - Gather = ONE asm block (8 loads + internal vmcnt(0)) into A-frags.
// - 4 syncs/step (was 5): MLP2 replicated across members (W2 in LDS),
//   y->x(t+1) transpose via block-private L2 scratch (no sync).

typedef __attribute__((ext_vector_type(8))) short short8;   // 8 x bf16
typedef __attribute__((ext_vector_type(4))) float f32x4;

#define TT   256
#define NTHR 512
#define NBLK 256

// packed-weight fragment bases (in 64-lane-frag units; elements = frag*8)
#define FB_WI0  0        // [768 x  64], KT=2
#define FB_WH0  6144     // [768 x 256], KT=8
#define FB_WI1  30720
#define FB_WH1  55296
#define FB_WI2  79872
#define FB_WH2  104448
#define FB_W1   129024   // [256 x 256]
#define FB_W2   137216   // [ 64 x 256]
#define TOTAL_FRAGS 139264

// d_ws layout (bytes)
#define OFF_FLAGS 2228224u               // 4 KB of u32 flags
#define OFF_H0    (OFF_FLAGS + 4096u)    // [2048][256] bf16 = 1 MB
#define OFF_H1    (OFF_H0 + 1048576u)
#define OFF_H2    (OFF_H1 + 1048576u)
#define OFF_A1    (OFF_H2 + 1048576u)    // [2048][256] bf16
#define OFF_Y     (OFF_A1 + 1048576u)    // [256 blocks][128][64] bf16 = 4 MB

// LDS weight-frag segment bases (1KB frags)
#define WH0_F 0
#define WI1_F 24
#define WH1_F 48
#define WI2_F 72
#define WH2_F 96
#define W2_F  120   // 32 frags
#define XW_F  152   // 6 frags -> 158 total = 161,792 B

__device__ __forceinline__ short bf16_rne(float v) {
  union { float f; unsigned u; } c; c.f = v;
  unsigned u = c.u;
  u += 0x7FFFu + ((u >> 16) & 1u);
  return (short)(u >> 16);
}
__device__ __forceinline__ float fast_sigmoid(float x) {
  return 1.0f / (1.0f + __expf(-x));
}
__device__ __forceinline__ float fast_tanh(float x) {
  return 1.0f - 2.0f / (__expf(2.0f * x) + 1.0f);
}

__device__ __forceinline__ void gll(const short* src, short* ldst) {
  __builtin_amdgcn_global_load_lds(
      (const __attribute__((address_space(1))) void*)src,
      (__attribute__((address_space(3))) void*)ldst, 16, 0, 0);
}
__device__ __forceinline__ void vm0() {
  asm volatile("s_waitcnt vmcnt(0)" ::: "memory");
  __builtin_amdgcn_sched_barrier(0);
}

// coherent store (write-through to device coherent point), 2 bytes
__device__ __forceinline__ void gstore_ic(short* g, short v) {
  asm volatile("global_store_short %0, %1, off sc0 sc1" :: "v"(g), "v"(v) : "memory");
}

// one-shot coherent gather: 8 x 16B A-frags, values complete at asm end
__device__ __forceinline__ void gather8_ic(const short* base, short8 (&f)[8]) {
  asm volatile(
      "global_load_dwordx4 %0, %8, off sc0 sc1\n\t"
      "global_load_dwordx4 %1, %8, off offset:64 sc0 sc1\n\t"
      "global_load_dwordx4 %2, %8, off offset:128 sc0 sc1\n\t"
      "global_load_dwordx4 %3, %8, off offset:192 sc0 sc1\n\t"
      "global_load_dwordx4 %4, %8, off offset:256 sc0 sc1\n\t"
      "global_load_dwordx4 %5, %8, off offset:320 sc0 sc1\n\t"
      "global_load_dwordx4 %6, %8, off offset:384 sc0 sc1\n\t"
      "global_load_dwordx4 %7, %8, off offset:448 sc0 sc1\n\t"
      "s_waitcnt vmcnt(0)"
      : "=&v"(f[0]), "=&v"(f[1]), "=&v"(f[2]), "=&v"(f[3]),
        "=&v"(f[4]), "=&v"(f[5]), "=&v"(f[6]), "=&v"(f[7])
      : "v"(base) : "memory");
}

// block-local L2 readback (own block's writes; bypass L1 only)
__device__ __forceinline__ void gather2_l2(const short* base, short8& a, short8& b) {
  asm volatile(
      "global_load_dwordx4 %0, %2, off sc0\n\t"
      "global_load_dwordx4 %1, %2, off offset:64 sc0\n\t"
      "s_waitcnt vmcnt(0)"
      : "=&v"(a), "=&v"(b) : "v"(base) : "memory");
}

__device__ __forceinline__ void flag_add(unsigned* f) {
  unsigned one = 1u;
  asm volatile("global_atomic_add %0, %1, off sc1" :: "v"(f), "v"(one) : "memory");
}
__device__ __forceinline__ unsigned flag_read(unsigned* f) {
  unsigned v;
  asm volatile("global_load_dword %0, %1, off sc0 sc1\n\ts_waitcnt vmcnt(0)"
               : "=&v"(v) : "v"(f) : "memory");
  return v;
}

// group barrier: all 16 member blocks arrive; no cache-walk fences
__device__ __forceinline__ void group_sync(unsigned* flag, unsigned target) {
  vm0();                // this wave's coherent stores acked at IC
  __syncthreads();      // whole block drained (implicit vmcnt0 per wave)
  if (threadIdx.x == 0) {
    flag_add(flag);
    while (flag_read(flag) < target) __builtin_amdgcn_s_sleep(1);
  }
  __syncthreads();
}

struct CB4 { float brz, bzz, bin, bhn; };
__device__ __forceinline__ CB4 make_cb4(const float* bi, const float* bh, int col) {
  CB4 cb;
  cb.brz = bi[col] + bh[col];
  cb.bzz = bi[256 + col] + bh[256 + col];
  cb.bin = bi[512 + col];
  cb.bhn = bh[512 + col];
  return cb;
}

__global__ void pack_weights(const float* __restrict__ Wi0, const float* __restrict__ Wh0,
                             const float* __restrict__ Wih12, const float* __restrict__ Whh12,
                             const float* __restrict__ W1, const float* __restrict__ W2,
                             short* __restrict__ outp)
{
  int f = blockIdx.x * blockDim.x + threadIdx.x;
  if (f >= TOTAL_FRAGS) return;
  const float* src; int K; int rel;
  if (f < FB_WH0)        { src = Wi0;            K = 64;  rel = f; }
  else if (f < FB_WI1)   { src = Wh0;            K = 256; rel = f - FB_WH0; }
  else if (f < FB_WH1)   { src = Wih12;          K = 256; rel = f - FB_WI1; }
  else if (f < FB_WI2)   { src = Whh12;          K = 256; rel = f - FB_WH1; }
  else if (f < FB_WH2)   { src = Wih12 + 196608; K = 256; rel = f - FB_WI2; }
  else if (f < FB_W1)    { src = Whh12 + 196608; K = 256; rel = f - FB_WH2; }
  else if (f < FB_W2)    { src = W1;             K = 256; rel = f - FB_W1; }
  else                   { src = W2;             K = 256; rel = f - FB_W2; }
  int lane = rel & 63;
  int q = rel >> 6;
  int KT = K >> 5;
  int kt = q % KT;
  int nt = q / KT;
  int n  = nt * 16 + (lane & 15);
  int k0 = kt * 32 + (lane >> 4) * 8;
  short8 v;
#pragma unroll
  for (int e = 0; e < 8; ++e) v[e] = bf16_rne(src[(size_t)n * K + k0 + e]);
  *(short8*)(outp + (size_t)f * 8) = v;
}

__global__ void zero_flags(unsigned* f) {
  if (threadIdx.x < 1024) f[threadIdx.x] = 0u;
}

#define MFMA(a, b, acc) __builtin_amdgcn_mfma_f32_16x16x32_bf16((a), (b), (acc), 0, 0, 0)
#define LDSF(idx) (*(const short8*)(wlds + (idx) * 512 + lane * 8))

#define GATE_UPDATE(agi, agh, cb, hm, hg)                                    \
  _Pragma("unroll") for (int j = 0; j < 4; ++j) {                            \
    float r_ = fast_sigmoid(agi[0][j] + agh[0][j] + cb.brz);                 \
    float z_ = fast_sigmoid(agi[1][j] + agh[1][j] + cb.bzz);                 \
    float n_ = fast_tanh(agi[2][j] + cb.bin + r_ * (agh[2][j] + cb.bhn));    \
    float h_ = n_ + z_ * (hm[j] - n_);                                       \
    hm[j] = h_;                                                              \
    gstore_ic(hg + (size_t)(grow0 + lhi * 4 + j) * 256 + col, bf16_rne(h_)); \
  }

__global__ __launch_bounds__(NTHR, 2)
void timegan_shard(const float* __restrict__ noise, char* __restrict__ ws,
                   const float* __restrict__ b_ih0, const float* __restrict__ b_hh0,
                   const float* __restrict__ b_ih12, const float* __restrict__ b_hh12,
                   const float* __restrict__ b1v, const float* __restrict__ b2v,
                   float* __restrict__ out)
{
  __shared__ __align__(16) short wlds[158 * 512];    // 161,792 B

  const short* wpack = (const short*)ws;
  unsigned* flags = (unsigned*)(ws + OFF_FLAGS);
  short* h0g = (short*)(ws + OFF_H0);
  short* h1g = (short*)(ws + OFF_H1);
  short* h2g = (short*)(ws + OFF_H2);
  short* a1g = (short*)(ws + OFF_A1);
  short* yg  = (short*)(ws + OFF_Y);

  const int tid = threadIdx.x;
  const int lane = tid & 63, w = tid >> 6;
  const int l15 = lane & 15, lhi = lane >> 4;
  const int gg = blockIdx.x & 15;        // group (batch slice)
  const int m  = blockIdx.x >> 4;        // member (column shard)
  const int grow0 = gg * 128 + w * 16;   // this wave's first global row
  const int col = m * 16 + l15;          // this lane's shard column
  unsigned* gflag = flags + gg * 8;
  short* ybb = yg + (size_t)blockIdx.x * 128 * 64;   // block-private bounce

  // ---- one-time: LDS weight shard (wave 0 issues the DMA) ----
  if (w == 0) {
    int dst = 0;
    const int fbs[5] = {FB_WH0, FB_WI1, FB_WH1, FB_WI2, FB_WH2};
    for (int s = 0; s < 5; ++s)
      for (int g = 0; g < 3; ++g)
        for (int kt = 0; kt < 8; ++kt) {
          gll(wpack + ((size_t)fbs[s] + (size_t)((g * 16 + m) * 8 + kt) * 64 + lane) * 8,
              wlds + dst * 512);
          ++dst;
        }
    for (int nt = 0; nt < 4; ++nt)                      // W2 (full)
      for (int kt = 0; kt < 8; ++kt) {
        gll(wpack + ((size_t)FB_W2 + (nt * 8 + kt) * 64 + lane) * 8, wlds + dst * 512);
        ++dst;
      }
    for (int g = 0; g < 3; ++g)                         // Wi0 shard
      for (int kt = 0; kt < 2; ++kt) {
        gll(wpack + ((size_t)FB_WI0 + ((g * 16 + m) * 2 + kt) * 64 + lane) * 8,
            wlds + dst * 512);
        ++dst;
      }
  }

  // ---- register weights: W1 shard (8 frags) ----
  short8 w1f[8];
#pragma unroll
  for (int kt = 0; kt < 8; ++kt)
    w1f[kt] = *(const short8*)(wpack + ((size_t)FB_W1 + (m * 8 + kt) * 64 + lane) * 8);

  // ---- x frags from noise ----
  short8 xf[2];
  {
    const float* np = noise + (size_t)(grow0 + l15) * 64;
#pragma unroll
    for (int kt = 0; kt < 2; ++kt) {
      f32x4 u0 = *(const f32x4*)(np + kt * 32 + lhi * 8);
      f32x4 u1 = *(const f32x4*)(np + kt * 32 + lhi * 8 + 4);
      short8 v;
#pragma unroll
      for (int e = 0; e < 4; ++e) { v[e] = bf16_rne(u0[e]); v[4 + e] = bf16_rne(u1[e]); }
      xf[kt] = v;
    }
  }

  // ---- biases ----
  CB4 cb0 = make_cb4(b_ih0, b_hh0, col);
  CB4 cb1 = make_cb4(b_ih12, b_hh12, col);
  CB4 cb2 = make_cb4(b_ih12 + 768, b_hh12 + 768, col);
  float bm1 = b1v[col];
  float bm2v[4];
#pragma unroll
  for (int nt = 0; nt < 4; ++nt) bm2v[nt] = b2v[nt * 16 + l15];

  // ---- persistent state ----
  short8 h0f[8], h1f[8], h2f[8];
  float hm0[4], hm1[4], hm2[4];
  {
    short8 z8 = {0, 0, 0, 0, 0, 0, 0, 0};
#pragma unroll
    for (int kt = 0; kt < 8; ++kt) { h0f[kt] = z8; h1f[kt] = z8; h2f[kt] = z8; }
#pragma unroll
    for (int j = 0; j < 4; ++j) { hm0[j] = 0.f; hm1[j] = 0.f; hm2[j] = 0.f; }
  }

  vm0();
  __syncthreads();

  const f32x4 z4 = {0.f, 0.f, 0.f, 0.f};
  const int rowoff = (grow0 + l15) * 256 + lhi * 8;   // gather base (shorts)

#pragma unroll 1
  for (int t = 0; t < TT; ++t) {
    const unsigned tgt = 16u * (unsigned)(t + 1);

    // ===== P0: cell 0 =====
    {
      f32x4 agi[3] = {z4, z4, z4}, agh[3] = {z4, z4, z4};
#pragma unroll
      for (int g = 0; g < 3; ++g) {
        agi[g] = MFMA(xf[0], LDSF(XW_F + g * 2 + 0), agi[g]);
        agi[g] = MFMA(xf[1], LDSF(XW_F + g * 2 + 1), agi[g]);
      }
#pragma unroll
      for (int kt = 0; kt < 8; ++kt)
#pragma unroll
        for (int g = 0; g < 3; ++g)
          agh[g] = MFMA(h0f[kt], LDSF(WH0_F + g * 8 + kt), agh[g]);
      GATE_UPDATE(agi, agh, cb0, hm0, h0g)
    }
    group_sync(gflag + 0, tgt);
    gather8_ic(h0g + rowoff, h0f);

    // ===== P1: cell 1 =====
    {
      f32x4 agi[3] = {z4, z4, z4}, agh[3] = {z4, z4, z4};
#pragma unroll
      for (int kt = 0; kt < 8; ++kt)
#pragma unroll
        for (int g = 0; g < 3; ++g) {
          agi[g] = MFMA(h0f[kt], LDSF(WI1_F + g * 8 + kt), agi[g]);
          agh[g] = MFMA(h1f[kt], LDSF(WH1_F + g * 8 + kt), agh[g]);
        }
      GATE_UPDATE(agi, agh, cb1, hm1, h1g)
    }
    group_sync(gflag + 1, tgt);
    gather8_ic(h1g + rowoff, h1f);

    // ===== P2: cell 2 =====
    {
      f32x4 agi[3] = {z4, z4, z4}, agh[3] = {z4, z4, z4};
#pragma unroll
      for (int kt = 0; kt < 8; ++kt)
#pragma unroll
        for (int g = 0; g < 3; ++g) {
          agi[g] = MFMA(h1f[kt], LDSF(WI2_F + g * 8 + kt), agi[g]);
          agh[g] = MFMA(h2f[kt], LDSF(WH2_F + g * 8 + kt), agh[g]);
        }
      GATE_UPDATE(agi, agh, cb2, hm2, h2g)
    }
    group_sync(gflag + 2, tgt);
    gather8_ic(h2g + rowoff, h2f);

    // ===== P3: MLP1 (sharded cols) =====
    {
      f32x4 am = z4;
#pragma unroll
      for (int kt = 0; kt < 8; ++kt) am = MFMA(h2f[kt], w1f[kt], am);
#pragma unroll
      for (int j = 0; j < 4; ++j) {
        float v = fmaxf(am[j] + bm1, 0.f);
        gstore_ic(a1g + (size_t)(grow0 + lhi * 4 + j) * 256 + col, bf16_rne(v));
      }
    }
    group_sync(gflag + 3, tgt);
    short8 af[8];
    gather8_ic(a1g + rowoff, af);

    // ===== P4: MLP2 replicated (own rows); y bounce -> x(t+1) =====
#pragma unroll
    for (int nt = 0; nt < 4; ++nt) {
      f32x4 ay = z4;
#pragma unroll
      for (int kt = 0; kt < 8; ++kt) ay = MFMA(af[kt], LDSF(W2_F + nt * 8 + kt), ay);
#pragma unroll
      for (int j = 0; j < 4; ++j) {
        int grow = grow0 + lhi * 4 + j;
        float y = fast_tanh(ay[j] + bm2v[nt]);
        if (m == 0) out[((size_t)grow * TT + t) * 64 + nt * 16 + l15] = y;
        ybb[(w * 16 + lhi * 4 + j) * 64 + nt * 16 + l15] = bf16_rne(y);
      }
    }
    if (t < TT - 1) {
      vm0();   // own bounce-stores visible in own L2
      gather2_l2(ybb + (w * 16 + l15) * 64 + lhi * 8, xf[0], xf[1]);
    }
  }
}

extern "C" void kernel_launch(void* const* d_in, const int* in_sizes, int n_in,
                              void* d_out, int out_size, void* d_ws, size_t ws_size,
                              hipStream_t stream)
{
  const float* noise  = (const float*)d_in[0];
  const float* W_ih0  = (const float*)d_in[1];
  const float* W_hh0  = (const float*)d_in[2];
  const float* b_ih0  = (const float*)d_in[3];
  const float* b_hh0  = (const float*)d_in[4];
  const float* W_ih12 = (const float*)d_in[5];
  const float* W_hh12 = (const float*)d_in[6];
  const float* b_ih12 = (const float*)d_in[7];
  const float* b_hh12 = (const float*)d_in[8];
  const float* W1     = (const float*)d_in[9];
  const float* b1     = (const float*)d_in[10];
  const float* W2     = (const float*)d_in[11];
  const float* b2     = (const float*)d_in[12];
  float* out = (float*)d_out;
  char* ws = (char*)d_ws;
  short* wpack = (short*)d_ws;

  zero_flags<<<1, 1024, 0, stream>>>((unsigned*)(ws + OFF_FLAGS));
  pack_weights<<<(TOTAL_FRAGS + 255) / 256, 256, 0, stream>>>(
      W_ih0, W_hh0, W_ih12, W_hh12, W1, W2, wpack);

  timegan_shard<<<NBLK, NTHR, 0, stream>>>(
      noise, ws, b_ih0, b_hh0, b_ih12, b_hh12, b1, b2, out);
}

// Round 11
// 5208.427 us; speedup vs baseline: 5.2101x; 1.0502x over previous
//
#include <hip/hip_runtime.h>
#include <hip/hip_bf16.h>

// TimeGAN generator: 3-layer GRU (H=256) + feedback MLP, B=2048, T=256.
// Round 11: R8's proven structure + data path VERBATIM (sc0 sc1 stores and
// gathers, atomic IC barrier as fallback). One change: the group barrier.
// Fast barrier = un-flagged global_atomic_add arrive + poll via RETURNING
// atomic-add-0 sc0 (L2-level RMW read -> always fresh, no L1/load anywhere;
// R9/R10 hangs were L1-frozen sc0 poll LOADS). Engaged only when the group's
// 16 blocks verify same-XCD residency (HW_REG_XCC_ID). Replay-safe via
// RELATIVE targets: slot base snapshotted between two R8-protocol IC
// barriers; wait on (v - base) >= 16*(t+1). Every wrong-assumption branch
// degrades to R8 semantics (correct, ~5.5ms), never hang.

typedef __attribute__((ext_vector_type(8))) short short8;   // 8 x bf16
typedef __attribute__((ext_vector_type(4))) float f32x4;

#define TT   256
#define NTHR 512
#define NBLK 256

// packed-weight fragment bases (in 64-lane-frag units; elements = frag*8)
#define FB_WI0  0        // [768 x  64], KT=2
#define FB_WH0  6144     // [768 x 256], KT=8
#define FB_WI1  30720
#define FB_WH1  55296
#define FB_WI2  79872
#define FB_WH2  104448
#define FB_W1   129024   // [256 x 256]
#define FB_W2   137216   // [ 64 x 256]
#define TOTAL_FRAGS 139264

// d_ws layout (bytes)
#define OFF_FLAGS 2228224u               // 16 KB flag region
#define OFF_H0    (OFF_FLAGS + 16384u)   // [2048][256] bf16 = 1 MB
#define OFF_H1    (OFF_H0 + 1048576u)
#define OFF_H2    (OFF_H1 + 1048576u)
#define OFF_A1    (OFF_H2 + 1048576u)    // [2048][256] bf16
#define OFF_Y     (OFF_A1 + 1048576u)    // [256 blocks][128][64] bf16 = 4 MB
// flag region (u32 index):
//   [gg*64 + p]          p=0..3  FAST slots (exclusive 256B line per group)
//   [1024 + gg*8 + p]    p=0..3  IC slots for slow mode (R8 layout/semantics)
//   [1280 + gg*16 + q]   q=0..1  init IC-barrier slots
//   [1792 + bid]                 per-block XCC id

// LDS weight-frag segment bases (1KB frags)
#define WH0_F 0
#define WI1_F 24
#define WH1_F 48
#define WI2_F 72
#define WH2_F 96
#define W2_F  120   // 32 frags
#define XW_F  152   // 6 frags -> 158 total = 161,792 B

__device__ __forceinline__ short bf16_rne(float v) {
  union { float f; unsigned u; } c; c.f = v;
  unsigned u = c.u;
  u += 0x7FFFu + ((u >> 16) & 1u);
  return (short)(u >> 16);
}
__device__ __forceinline__ float fast_sigmoid(float x) {
  return 1.0f / (1.0f + __expf(-x));
}
__device__ __forceinline__ float fast_tanh(float x) {
  return 1.0f - 2.0f / (__expf(2.0f * x) + 1.0f);
}

__device__ __forceinline__ void gll(const short* src, short* ldst) {
  __builtin_amdgcn_global_load_lds(
      (const __attribute__((address_space(1))) void*)src,
      (__attribute__((address_space(3))) void*)ldst, 16, 0, 0);
}
__device__ __forceinline__ void vm0() {
  asm volatile("s_waitcnt vmcnt(0)" ::: "memory");
  __builtin_amdgcn_sched_barrier(0);
}

// ---- R8-proven IC-domain primitives (verbatim) ----
__device__ __forceinline__ void gstore_ic(short* g, short v) {
  asm volatile("global_store_short %0, %1, off sc0 sc1" :: "v"(g), "v"(v) : "memory");
}
__device__ __forceinline__ void gather8_ic(const short* base, short8 (&f)[8]) {
  asm volatile(
      "global_load_dwordx4 %0, %8, off sc0 sc1\n\t"
      "global_load_dwordx4 %1, %8, off offset:64 sc0 sc1\n\t"
      "global_load_dwordx4 %2, %8, off offset:128 sc0 sc1\n\t"
      "global_load_dwordx4 %3, %8, off offset:192 sc0 sc1\n\t"
      "global_load_dwordx4 %4, %8, off offset:256 sc0 sc1\n\t"
      "global_load_dwordx4 %5, %8, off offset:320 sc0 sc1\n\t"
      "global_load_dwordx4 %6, %8, off offset:384 sc0 sc1\n\t"
      "global_load_dwordx4 %7, %8, off offset:448 sc0 sc1\n\t"
      "s_waitcnt vmcnt(0)"
      : "=&v"(f[0]), "=&v"(f[1]), "=&v"(f[2]), "=&v"(f[3]),
        "=&v"(f[4]), "=&v"(f[5]), "=&v"(f[6]), "=&v"(f[7])
      : "v"(base) : "memory");
}
__device__ __forceinline__ void gather2_l2(const short* base, short8& a, short8& b) {
  asm volatile(
      "global_load_dwordx4 %0, %2, off sc0\n\t"
      "global_load_dwordx4 %1, %2, off offset:64 sc0\n\t"
      "s_waitcnt vmcnt(0)"
      : "=&v"(a), "=&v"(b) : "v"(base) : "memory");
}
__device__ __forceinline__ void flag_add_ic(unsigned* f) {
  unsigned one = 1u;
  asm volatile("global_atomic_add %0, %1, off sc1" :: "v"(f), "v"(one) : "memory");
}
__device__ __forceinline__ unsigned flag_read_ic(unsigned* f) {
  unsigned v;
  asm volatile("global_load_dword %0, %1, off sc0 sc1\n\ts_waitcnt vmcnt(0)"
               : "=&v"(v) : "v"(f) : "memory");
  return v;
}
__device__ __forceinline__ void group_sync_ic(unsigned* flag, unsigned target) {
  vm0();
  __syncthreads();
  if (threadIdx.x == 0) {
    flag_add_ic(flag);
    while (flag_read_ic(flag) < target) __builtin_amdgcn_s_sleep(1);
  }
  __syncthreads();
}

// ---- fast-barrier primitives: atomics only (atomics never touch L1) ----
__device__ __forceinline__ void flag_add_l2(unsigned* f) {
  unsigned one = 1u;
  asm volatile("global_atomic_add %0, %1, off" :: "v"(f), "v"(one) : "memory");
}
__device__ __forceinline__ unsigned flag_rmwread_l2(unsigned* f) {
  unsigned v; unsigned zero = 0u;
  asm volatile("global_atomic_add %0, %1, %2, off sc0\n\ts_waitcnt vmcnt(0)"
               : "=&v"(v) : "v"(f), "v"(zero) : "memory");
  return v;
}
__device__ __forceinline__ void group_sync_fast(unsigned* flag, unsigned base,
                                                unsigned delta) {
  vm0();                 // data stores acked at IC before arrival is visible
  __syncthreads();
  if (threadIdx.x == 0) {
    flag_add_l2(flag);
    while (flag_rmwread_l2(flag) - base < delta) __builtin_amdgcn_s_sleep(1);
  }
  __syncthreads();
}

struct CB4 { float brz, bzz, bin, bhn; };
__device__ __forceinline__ CB4 make_cb4(const float* bi, const float* bh, int col) {
  CB4 cb;
  cb.brz = bi[col] + bh[col];
  cb.bzz = bi[256 + col] + bh[256 + col];
  cb.bin = bi[512 + col];
  cb.bhn = bh[512 + col];
  return cb;
}

__global__ void pack_weights(const float* __restrict__ Wi0, const float* __restrict__ Wh0,
                             const float* __restrict__ Wih12, const float* __restrict__ Whh12,
                             const float* __restrict__ W1, const float* __restrict__ W2,
                             short* __restrict__ outp)
{
  int f = blockIdx.x * blockDim.x + threadIdx.x;
  if (f >= TOTAL_FRAGS) return;
  const float* src; int K; int rel;
  if (f < FB_WH0)        { src = Wi0;            K = 64;  rel = f; }
  else if (f < FB_WI1)   { src = Wh0;            K = 256; rel = f - FB_WH0; }
  else if (f < FB_WH1)   { src = Wih12;          K = 256; rel = f - FB_WI1; }
  else if (f < FB_WI2)   { src = Whh12;          K = 256; rel = f - FB_WH1; }
  else if (f < FB_WH2)   { src = Wih12 + 196608; K = 256; rel = f - FB_WI2; }
  else if (f < FB_W1)    { src = Whh12 + 196608; K = 256; rel = f - FB_WH2; }
  else if (f < FB_W2)    { src = W1;             K = 256; rel = f - FB_W1; }
  else                   { src = W2;             K = 256; rel = f - FB_W2; }
  int lane = rel & 63;
  int q = rel >> 6;
  int KT = K >> 5;
  int kt = q % KT;
  int nt = q / KT;
  int n  = nt * 16 + (lane & 15);
  int k0 = kt * 32 + (lane >> 4) * 8;
  short8 v;
#pragma unroll
  for (int e = 0; e < 8; ++e) v[e] = bf16_rne(src[(size_t)n * K + k0 + e]);
  *(short8*)(outp + (size_t)f * 8) = v;
}

__global__ void zero_flags(unsigned* f) {
  int i = threadIdx.x;
#pragma unroll
  for (int k = 0; k < 4; ++k) f[i + 1024 * k] = 0u;
}

#define MFMA(a, b, acc) __builtin_amdgcn_mfma_f32_16x16x32_bf16((a), (b), (acc), 0, 0, 0)
#define LDSF(idx) (*(const short8*)(wlds + (idx) * 512 + lane * 8))

#define GATE_UPDATE(agi, agh, cb, hm, hg)                                    \
  _Pragma("unroll") for (int j = 0; j < 4; ++j) {                            \
    float r_ = fast_sigmoid(agi[0][j] + agh[0][j] + cb.brz);                 \
    float z_ = fast_sigmoid(agi[1][j] + agh[1][j] + cb.bzz);                 \
    float n_ = fast_tanh(agi[2][j] + cb.bin + r_ * (agh[2][j] + cb.bhn));    \
    float h_ = n_ + z_ * (hm[j] - n_);                                       \
    hm[j] = h_;                                                              \
    gstore_ic(hg + (size_t)(grow0 + lhi * 4 + j) * 256 + col, bf16_rne(h_)); \
  }

#define BARRIER(p)                                                            \
  do {                                                                        \
    if constexpr (FAST) group_sync_fast(fsl + (p), bs[p], 16u * (t + 1));     \
    else                group_sync_ic(isl + (p), 16u * (t + 1));              \
  } while (0)

template<bool FAST>
__device__ void mainloop(
    const short* wlds,
    short* h0g, short* h1g, short* h2g, short* a1g, short* ybb,
    float* __restrict__ out,
    unsigned* fsl, unsigned* isl, const unsigned* bs,
    short8 (&xf)[2], short8 (&h0f)[8], short8 (&h1f)[8], short8 (&h2f)[8],
    short8 (&w1f)[8],
    float (&hm0)[4], float (&hm1)[4], float (&hm2)[4],
    const CB4 cb0, const CB4 cb1, const CB4 cb2,
    float bm1, const float (&bm2v)[4],
    int grow0, int col, int rowoff, int lane, int l15, int lhi, int w, int m)
{
  const f32x4 z4 = {0.f, 0.f, 0.f, 0.f};

#pragma unroll 1
  for (unsigned t = 0; t < TT; ++t) {
    // ===== P0: cell 0 =====
    {
      f32x4 agi[3] = {z4, z4, z4}, agh[3] = {z4, z4, z4};
#pragma unroll
      for (int g = 0; g < 3; ++g) {
        agi[g] = MFMA(xf[0], LDSF(XW_F + g * 2 + 0), agi[g]);
        agi[g] = MFMA(xf[1], LDSF(XW_F + g * 2 + 1), agi[g]);
      }
#pragma unroll
      for (int kt = 0; kt < 8; ++kt)
#pragma unroll
        for (int g = 0; g < 3; ++g)
          agh[g] = MFMA(h0f[kt], LDSF(WH0_F + g * 8 + kt), agh[g]);
      GATE_UPDATE(agi, agh, cb0, hm0, h0g)
    }
    BARRIER(0);
    gather8_ic(h0g + rowoff, h0f);

    // ===== P1: cell 1 =====
    {
      f32x4 agi[3] = {z4, z4, z4}, agh[3] = {z4, z4, z4};
#pragma unroll
      for (int kt = 0; kt < 8; ++kt)
#pragma unroll
        for (int g = 0; g < 3; ++g) {
          agi[g] = MFMA(h0f[kt], LDSF(WI1_F + g * 8 + kt), agi[g]);
          agh[g] = MFMA(h1f[kt], LDSF(WH1_F + g * 8 + kt), agh[g]);
        }
      GATE_UPDATE(agi, agh, cb1, hm1, h1g)
    }
    BARRIER(1);
    gather8_ic(h1g + rowoff, h1f);

    // ===== P2: cell 2 =====
    {
      f32x4 agi[3] = {z4, z4, z4}, agh[3] = {z4, z4, z4};
#pragma unroll
      for (int kt = 0; kt < 8; ++kt)
#pragma unroll
        for (int g = 0; g < 3; ++g) {
          agi[g] = MFMA(h1f[kt], LDSF(WI2_F + g * 8 + kt), agi[g]);
          agh[g] = MFMA(h2f[kt], LDSF(WH2_F + g * 8 + kt), agh[g]);
        }
      GATE_UPDATE(agi, agh, cb2, hm2, h2g)
    }
    BARRIER(2);
    gather8_ic(h2g + rowoff, h2f);

    // ===== P3: MLP1 (sharded cols) =====
    {
      f32x4 am = z4;
#pragma unroll
      for (int kt = 0; kt < 8; ++kt) am = MFMA(h2f[kt], w1f[kt], am);
#pragma unroll
      for (int j = 0; j < 4; ++j) {
        float v = fmaxf(am[j] + bm1, 0.f);
        gstore_ic(a1g + (size_t)(grow0 + lhi * 4 + j) * 256 + col, bf16_rne(v));
      }
    }
    BARRIER(3);
    short8 af[8];
    gather8_ic(a1g + rowoff, af);

    // ===== P4: MLP2 replicated (own rows); y bounce -> x(t+1) =====
#pragma unroll
    for (int nt = 0; nt < 4; ++nt) {
      f32x4 ay = z4;
#pragma unroll
      for (int kt = 0; kt < 8; ++kt) ay = MFMA(af[kt], LDSF(W2_F + nt * 8 + kt), ay);
#pragma unroll
      for (int j = 0; j < 4; ++j) {
        int grow = grow0 + lhi * 4 + j;
        float y = fast_tanh(ay[j] + bm2v[nt]);
        if (m == 0) out[((size_t)grow * TT + t) * 64 + nt * 16 + l15] = y;
        ybb[(w * 16 + lhi * 4 + j) * 64 + nt * 16 + l15] = bf16_rne(y);
      }
    }
    if (t < TT - 1) {
      vm0();   // own bounce-stores visible in own L2 (R8-proven)
      gather2_l2(ybb + (w * 16 + l15) * 64 + lhi * 8, xf[0], xf[1]);
    }
  }
}

__global__ __launch_bounds__(NTHR, 2)
void timegan_shard(const float* __restrict__ noise, char* __restrict__ ws,
                   const float* __restrict__ b_ih0, const float* __restrict__ b_hh0,
                   const float* __restrict__ b_ih12, const float* __restrict__ b_hh12,
                   const float* __restrict__ b1v, const float* __restrict__ b2v,
                   float* __restrict__ out)
{
  __shared__ __align__(16) short wlds[158 * 512];    // 161,792 B
  __shared__ int fastsh;
  __shared__ unsigned bsh[4];

  const short* wpack = (const short*)ws;
  unsigned* flags = (unsigned*)(ws + OFF_FLAGS);
  short* h0g = (short*)(ws + OFF_H0);
  short* h1g = (short*)(ws + OFF_H1);
  short* h2g = (short*)(ws + OFF_H2);
  short* a1g = (short*)(ws + OFF_A1);
  short* yg  = (short*)(ws + OFF_Y);

  const int tid = threadIdx.x;
  const int lane = tid & 63, w = tid >> 6;
  const int l15 = lane & 15, lhi = lane >> 4;
  const int bid = blockIdx.x;
  const int gg = bid & 15;               // group (batch slice)
  const int m  = bid >> 4;               // member (column shard)
  const int grow0 = gg * 128 + w * 16;   // this wave's first global row
  const int col = m * 16 + l15;          // this lane's shard column
  unsigned* fsl    = flags + gg * 64;              // fast slots (own 256B line)
  unsigned* isl    = flags + 1024 + gg * 8;        // IC slots (R8 layout)
  unsigned* initA  = flags + 1280 + gg * 16;       // init barrier slots
  unsigned* initB  = initA + 1;
  unsigned* xccids = flags + 1792;
  short* ybb = yg + (size_t)bid * 128 * 64;        // block-private bounce

  // ---- one-time: LDS weight shard (wave 0 issues the DMA) ----
  if (w == 0) {
    int dst = 0;
    const int fbs[5] = {FB_WH0, FB_WI1, FB_WH1, FB_WI2, FB_WH2};
    for (int s = 0; s < 5; ++s)
      for (int g = 0; g < 3; ++g)
        for (int kt = 0; kt < 8; ++kt) {
          gll(wpack + ((size_t)fbs[s] + (size_t)((g * 16 + m) * 8 + kt) * 64 + lane) * 8,
              wlds + dst * 512);
          ++dst;
        }
    for (int nt = 0; nt < 4; ++nt)                      // W2 (full)
      for (int kt = 0; kt < 8; ++kt) {
        gll(wpack + ((size_t)FB_W2 + (nt * 8 + kt) * 64 + lane) * 8, wlds + dst * 512);
        ++dst;
      }
    for (int g = 0; g < 3; ++g)                         // Wi0 shard
      for (int kt = 0; kt < 2; ++kt) {
        gll(wpack + ((size_t)FB_WI0 + ((g * 16 + m) * 2 + kt) * 64 + lane) * 8,
            wlds + dst * 512);
        ++dst;
      }
  }

  // ---- register weights: W1 shard (8 frags) ----
  short8 w1f[8];
#pragma unroll
  for (int kt = 0; kt < 8; ++kt)
    w1f[kt] = *(const short8*)(wpack + ((size_t)FB_W1 + (m * 8 + kt) * 64 + lane) * 8);

  // ---- x frags from noise ----
  short8 xf[2];
  {
    const float* np = noise + (size_t)(grow0 + l15) * 64;
#pragma unroll
    for (int kt = 0; kt < 2; ++kt) {
      f32x4 u0 = *(const f32x4*)(np + kt * 32 + lhi * 8);
      f32x4 u1 = *(const f32x4*)(np + kt * 32 + lhi * 8 + 4);
      short8 v;
#pragma unroll
      for (int e = 0; e < 4; ++e) { v[e] = bf16_rne(u0[e]); v[4 + e] = bf16_rne(u1[e]); }
      xf[kt] = v;
    }
  }

  // ---- biases ----
  CB4 cb0 = make_cb4(b_ih0, b_hh0, col);
  CB4 cb1 = make_cb4(b_ih12, b_hh12, col);
  CB4 cb2 = make_cb4(b_ih12 + 768, b_hh12 + 768, col);
  float bm1 = b1v[col];
  float bm2v[4];
#pragma unroll
  for (int nt = 0; nt < 4; ++nt) bm2v[nt] = b2v[nt * 16 + l15];

  // ---- persistent state ----
  short8 h0f[8], h1f[8], h2f[8];
  float hm0[4], hm1[4], hm2[4];
  {
    short8 z8 = {0, 0, 0, 0, 0, 0, 0, 0};
#pragma unroll
    for (int kt = 0; kt < 8; ++kt) { h0f[kt] = z8; h1f[kt] = z8; h2f[kt] = z8; }
#pragma unroll
    for (int j = 0; j < 4; ++j) { hm0[j] = 0.f; hm1[j] = 0.f; hm2[j] = 0.f; }
  }

  // ---- publish XCC id (IC domain, R8-proven ops) ----
  if (tid == 0) {
    unsigned xcc = 0;
    asm volatile("s_getreg_b32 %0, hwreg(HW_REG_XCC_ID)" : "=s"(xcc));
    unsigned* myid = xccids + bid;
    unsigned xv = xcc;
    asm volatile("global_store_dword %0, %1, off sc0 sc1" :: "v"(myid), "v"(xv) : "memory");
  }
  // IC barrier A: covers weight-DMA drain + xcc publish (entry vm0+barrier)
  group_sync_ic(initA, 16u);

  // ---- verify co-XCD residency of this group's 16 members ----
  if (tid < 64) {
    unsigned* xp = xccids + gg + 16 * (lane & 15);
    unsigned xv;
    asm volatile("global_load_dword %0, %1, off sc0 sc1\n\ts_waitcnt vmcnt(0)"
                 : "=&v"(xv) : "v"(xp) : "memory");
    unsigned ref = __shfl(xv, 0);
    int ok = __all(xv == ref);
    if (lane == 0) fastsh = ok;
  }
  __syncthreads();

  // ---- snapshot fast-slot bases (replay-safe relative targets) ----
  if (tid == 0 && fastsh) {
#pragma unroll
    for (int p = 0; p < 4; ++p) bsh[p] = flag_rmwread_l2(fsl + p);
  }
  // IC barrier B: all snapshots complete before any step-0 arrival
  group_sync_ic(initB, 16u);

  const bool fast = fastsh != 0;
  const int rowoff = (grow0 + l15) * 256 + lhi * 8;   // gather base (shorts)

  if (fast)
    mainloop<true>(wlds, h0g, h1g, h2g, a1g, ybb, out, fsl, isl, bsh,
                   xf, h0f, h1f, h2f, w1f, hm0, hm1, hm2,
                   cb0, cb1, cb2, bm1, bm2v,
                   grow0, col, rowoff, lane, l15, lhi, w, m);
  else
    mainloop<false>(wlds, h0g, h1g, h2g, a1g, ybb, out, fsl, isl, bsh,
                    xf, h0f, h1f, h2f, w1f, hm0, hm1, hm2,
                    cb0, cb1, cb2, bm1, bm2v,
                    grow0, col, rowoff, lane, l15, lhi, w, m);
}

extern "C" void kernel_launch(void* const* d_in, const int* in_sizes, int n_in,
                              void* d_out, int out_size, void* d_ws, size_t ws_size,
                              hipStream_t stream)
{
  const float* noise  = (const float*)d_in[0];
  const float* W_ih0  = (const float*)d_in[1];
  const float* W_hh0  = (const float*)d_in[2];
  const float* b_ih0  = (const float*)d_in[3];
  const float* b_hh0  = (const float*)d_in[4];
  const float* W_ih12 = (const float*)d_in[5];
  const float* W_hh12 = (const float*)d_in[6];
  const float* b_ih12 = (const float*)d_in[7];
  const float* b_hh12 = (const float*)d_in[8];
  const float* W1     = (const float*)d_in[9];
  const float* b1     = (const float*)d_in[10];
  const float* W2     = (const float*)d_in[11];
  const float* b2     = (const float*)d_in[12];
  float* out = (float*)d_out;
  char* ws = (char*)d_ws;
  short* wpack = (short*)d_ws;

  zero_flags<<<1, 1024, 0, stream>>>((unsigned*)(ws + OFF_FLAGS));
  pack_weights<<<(TOTAL_FRAGS + 255) / 256, 256, 0, stream>>>(
      W_ih0, W_hh0, W_ih12, W_hh12, W1, W2, wpack);

  timegan_shard<<<NBLK, NTHR, 0, stream>>>(
      noise, ws, b_ih0, b_hh0, b_ih12, b_hh12, b1, b2, out);
}